// Round 1
// baseline (1441.331 us; speedup 1.0000x reference)
//
#include <hip/hip_runtime.h>
#include <hip/hip_bf16.h>

#define N_NODES 16384
#define EDGE_CAP 128   // max expected degree ~97 (mean 65.5, sd 8.1; >7 sigma headroom)

typedef float f32x4 __attribute__((ext_vector_type(4)));

// ---------------------------------------------------------------------------
// Zero the per-row edge counters (ws arrives poisoned 0xAA).
// ---------------------------------------------------------------------------
__global__ void zero_cnts_kernel(int* __restrict__ cnts)
{
    int i = blockIdx.x * 256 + threadIdx.x;
    if (i < N_NODES) cnts[i] = 0;
}

// ---------------------------------------------------------------------------
// Fused encoder: per 4-row block (128 threads), entirely in LDS:
//   h1 = relu(x@w1+b1)   [4,64]
//   h  = relu(h1@w2+b2)  [4,128]  -> global (tail needs it)
//   hw = h@wg            [4,128]  -> global (spmm needs it)
// Replaces 3 linear_kernel launches + the 4 MB h1 round-trip.
// ---------------------------------------------------------------------------
__global__ void encoder_kernel(const float* __restrict__ x,
                               const float* __restrict__ w1, const float* __restrict__ b1,
                               const float* __restrict__ w2, const float* __restrict__ b2,
                               const float* __restrict__ wg,
                               float* __restrict__ h, float* __restrict__ hw)
{
    __shared__ float s_x [4 * 32];
    __shared__ float s_h1[4 * 64];
    __shared__ float s_h [4 * 128];
    const int row0 = blockIdx.x * 4;
    const int tid = threadIdx.x;     // 0..127

    // stage x: 4 rows x 32 = 128 contiguous floats
    s_x[tid] = x[(size_t)row0 * 32 + tid];
    __syncthreads();

    // h1 = relu(x @ w1 + b1): O=64. threads 0..63 -> rows 0,1; 64..127 -> rows 2,3
    {
        const int o  = tid & 63;
        const int rp = (tid >> 6) * 2;
        float b = b1[o];
        float a0 = b, a1 = b;
        #pragma unroll
        for (int k = 0; k < 32; ++k) {
            float w = w1[k * 64 + o];
            a0 = fmaf(s_x[rp * 32 + k],       w, a0);
            a1 = fmaf(s_x[(rp + 1) * 32 + k], w, a1);
        }
        s_h1[rp * 64 + o]       = fmaxf(a0, 0.0f);
        s_h1[(rp + 1) * 64 + o] = fmaxf(a1, 0.0f);
    }
    __syncthreads();

    // h = relu(h1 @ w2 + b2): O=128, all 128 threads, 4 rows
    {
        const int o = tid;
        float b = b2[o];
        float a0 = b, a1 = b, a2 = b, a3 = b;
        #pragma unroll 4
        for (int k = 0; k < 64; ++k) {
            float w = w2[k * 128 + o];
            a0 = fmaf(s_h1[k],        w, a0);
            a1 = fmaf(s_h1[64 + k],   w, a1);
            a2 = fmaf(s_h1[128 + k],  w, a2);
            a3 = fmaf(s_h1[192 + k],  w, a3);
        }
        a0 = fmaxf(a0, 0.0f); a1 = fmaxf(a1, 0.0f);
        a2 = fmaxf(a2, 0.0f); a3 = fmaxf(a3, 0.0f);
        s_h[o] = a0;  s_h[128 + o] = a1;  s_h[256 + o] = a2;  s_h[384 + o] = a3;
        h[(size_t)(row0 + 0) * 128 + o] = a0;
        h[(size_t)(row0 + 1) * 128 + o] = a1;
        h[(size_t)(row0 + 2) * 128 + o] = a2;
        h[(size_t)(row0 + 3) * 128 + o] = a3;
    }
    __syncthreads();

    // hw = h @ wg (no bias, no relu)
    {
        const int o = tid;
        float a0 = 0.0f, a1 = 0.0f, a2 = 0.0f, a3 = 0.0f;
        #pragma unroll 4
        for (int k = 0; k < 128; ++k) {
            float w = wg[k * 128 + o];
            a0 = fmaf(s_h[k],        w, a0);
            a1 = fmaf(s_h[128 + k],  w, a1);
            a2 = fmaf(s_h[256 + k],  w, a2);
            a3 = fmaf(s_h[384 + k],  w, a3);
        }
        hw[(size_t)(row0 + 0) * 128 + o] = a0;
        hw[(size_t)(row0 + 1) * 128 + o] = a1;
        hw[(size_t)(row0 + 2) * 128 + o] = a2;
        hw[(size_t)(row0 + 3) * 128 + o] = a3;
    }
}

// ---------------------------------------------------------------------------
// Upper-triangle adjacency scan (adj symmetric, zero diagonal): block i scans
// columns j > i only (537 MB HBM read — the irreducible term). Row-i-side
// edges are aggregated in LDS and flushed with ONE base-reservation atomic +
// coalesced writes; only the j-side needs a per-edge global atomic + 4 B
// scattered write. Non-temporal loads keep the read-once adj stream from
// evicting hw (needed by spmm next) out of L2/LLC.
// ---------------------------------------------------------------------------
__global__ void tri_scan_kernel(const float* __restrict__ adj,
                                int* __restrict__ edges,
                                int* __restrict__ cnts)
{
    __shared__ int s_cnt;
    __shared__ int s_base;
    __shared__ int s_list[EDGE_CAP];
    const int i = blockIdx.x;
    if (threadIdx.x == 0) s_cnt = 0;
    __syncthreads();

    const f32x4* rp = reinterpret_cast<const f32x4*>(adj + (size_t)i * N_NODES);
    const int v0 = (i + 1) >> 2;     // first float4 that can contain j > i
    for (int vi = v0 + threadIdx.x; vi < N_NODES / 4; vi += 256) {
        f32x4 v = __builtin_nontemporal_load(&rp[vi]);
        // 98.4% of float4s are all-zero: one branch skips the element loop
        if (v.x != 0.0f || v.y != 0.0f || v.z != 0.0f || v.w != 0.0f) {
            int base = vi * 4;
            #pragma unroll
            for (int q = 0; q < 4; ++q) {
                float val = (q == 0) ? v.x : (q == 1) ? v.y : (q == 2) ? v.z : v.w;
                int j = base + q;
                if (val != 0.0f && j > i) {
                    int p = atomicAdd(&s_cnt, 1);            // row-i side: LDS
                    if (p < EDGE_CAP) s_list[p] = j;
                    int pj = atomicAdd(&cnts[j], 1);         // row-j side: global
                    if (pj < EDGE_CAP) edges[(size_t)j * EDGE_CAP + pj] = i;
                }
            }
        }
    }
    __syncthreads();
    int c = s_cnt;
    if (c > EDGE_CAP) c = EDGE_CAP;                          // statistically impossible
    if (threadIdx.x == 0) s_base = atomicAdd(&cnts[i], c);
    __syncthreads();
    const int b = s_base;
    for (int k = threadIdx.x; k < c; k += 256) {
        int pos = b + k;
        if (pos < EDGE_CAP) edges[(size_t)i * EDGE_CAP + pos] = s_list[k];
    }
}

// ---------------------------------------------------------------------------
// SpMM + GCN normalization: xg[i,:] = relu(dinv_i * (sum_{j in N(i) u {i}}
// dinv_j * hw[j,:]) + bg), dinv_k = rsqrt(cnt_k + 1)  (A+I self loop).
// 4 rows per block (128 threads); each 32-lane quarter owns one row and reads
// hw rows as float4 (one dwordx4 per lane per neighbor: 4x fewer VMEM instrs
// than the scalar version). hw (8 MB) is L2/LLC resident.
// ---------------------------------------------------------------------------
__global__ void spmm_kernel(const float* __restrict__ hw,
                            const int* __restrict__ edges,
                            const int* __restrict__ cnts,
                            const float* __restrict__ bg,
                            float* __restrict__ xg)
{
    __shared__ int   s_e[4][EDGE_CAP];
    __shared__ float s_d[4][EDGE_CAP];
    const int r    = threadIdx.x >> 5;          // 0..3: row within block
    const int lane = threadIdx.x & 31;          // float4 index: features 4*lane..4*lane+3
    const int row  = blockIdx.x * 4 + r;

    int c = cnts[row];
    if (c > EDGE_CAP) c = EDGE_CAP;
    for (int k = lane; k < c; k += 32) {
        int j = edges[(size_t)row * EDGE_CAP + k];
        s_e[r][k] = j;
        s_d[r][k] = rsqrtf((float)cnts[j] + 1.0f);
    }
    __syncthreads();

    const f32x4* hw4 = reinterpret_cast<const f32x4*>(hw);
    const float di = rsqrtf((float)c + 1.0f);
    f32x4 v = hw4[(size_t)row * 32 + lane];     // self loop
    f32x4 acc;
    acc.x = di * v.x; acc.y = di * v.y; acc.z = di * v.z; acc.w = di * v.w;
    for (int k = 0; k < c; ++k) {
        float d = s_d[r][k];
        f32x4 u = hw4[(size_t)s_e[r][k] * 32 + lane];
        acc.x = fmaf(d, u.x, acc.x);
        acc.y = fmaf(d, u.y, acc.y);
        acc.z = fmaf(d, u.z, acc.z);
        acc.w = fmaf(d, u.w, acc.w);
    }

    const f32x4 b4 = reinterpret_cast<const f32x4*>(bg)[lane];
    f32x4 o;
    o.x = fmaxf(fmaf(di, acc.x, b4.x), 0.0f);
    o.y = fmaxf(fmaf(di, acc.y, b4.y), 0.0f);
    o.z = fmaxf(fmaf(di, acc.z, b4.z), 0.0f);
    o.w = fmaxf(fmaf(di, acc.w, b4.w), 0.0f);
    reinterpret_cast<f32x4*>(xg)[(size_t)row * 32 + lane] = o;
}

// ---------------------------------------------------------------------------
// Fused tail: per block of 4 rows (128 threads), entirely in LDS:
//   xd = relu(xg@wd+bd); p1 = relu([xd,h]@wp1+bp1); p2 = relu(p1@wp2+bp2);
//   out = p2@wo + bo.
// ---------------------------------------------------------------------------
__global__ void tail_kernel(const float* __restrict__ xg,
                            const float* __restrict__ h,
                            const float* __restrict__ wd,  const float* __restrict__ bd,
                            const float* __restrict__ wp1, const float* __restrict__ bp1,
                            const float* __restrict__ wp2, const float* __restrict__ bp2,
                            const float* __restrict__ wo,  const float* __restrict__ bo,
                            float* __restrict__ out)
{
    __shared__ float s_a[4 * 128];   // xg, then p1
    __shared__ float s_h[4 * 128];   // h
    __shared__ float s_b[4 * 128];   // xd, then p2 (uses first 4*64)
    const int row0 = blockIdx.x * 4;
    const int tid = threadIdx.x;     // 0..127

    for (int idx = tid; idx < 512; idx += 128) {
        int r = idx >> 7, k = idx & 127;
        s_a[idx] = xg[(size_t)(row0 + r) * 128 + k];
        s_h[idx] = h [(size_t)(row0 + r) * 128 + k];
    }
    __syncthreads();

    // xd = relu(xg @ wd + bd)  -> s_b
    {
        const int o = tid;
        float b = bd[o];
        float a0 = b, a1 = b, a2 = b, a3 = b;
        #pragma unroll 4
        for (int k = 0; k < 128; ++k) {
            float w = wd[(size_t)k * 128 + o];
            a0 = fmaf(s_a[k],       w, a0);
            a1 = fmaf(s_a[128 + k], w, a1);
            a2 = fmaf(s_a[256 + k], w, a2);
            a3 = fmaf(s_a[384 + k], w, a3);
        }
        __syncthreads();             // all reads of s_a (xg) done
        s_b[o]       = fmaxf(a0, 0.0f);
        s_b[128 + o] = fmaxf(a1, 0.0f);
        s_b[256 + o] = fmaxf(a2, 0.0f);
        s_b[384 + o] = fmaxf(a3, 0.0f);
    }
    __syncthreads();

    // p1 = relu([xd, h] @ wp1 + bp1)  -> s_a
    {
        const int o = tid;
        float b = bp1[o];
        float a0 = b, a1 = b, a2 = b, a3 = b;
        #pragma unroll 4
        for (int k = 0; k < 128; ++k) {
            float w = wp1[(size_t)k * 128 + o];          // xd half
            a0 = fmaf(s_b[k],       w, a0);
            a1 = fmaf(s_b[128 + k], w, a1);
            a2 = fmaf(s_b[256 + k], w, a2);
            a3 = fmaf(s_b[384 + k], w, a3);
        }
        #pragma unroll 4
        for (int k = 0; k < 128; ++k) {
            float w = wp1[(size_t)(128 + k) * 128 + o];  // h half
            a0 = fmaf(s_h[k],       w, a0);
            a1 = fmaf(s_h[128 + k], w, a1);
            a2 = fmaf(s_h[256 + k], w, a2);
            a3 = fmaf(s_h[384 + k], w, a3);
        }
        s_a[o]       = fmaxf(a0, 0.0f);
        s_a[128 + o] = fmaxf(a1, 0.0f);
        s_a[256 + o] = fmaxf(a2, 0.0f);
        s_a[384 + o] = fmaxf(a3, 0.0f);
    }
    __syncthreads();

    // p2 = relu(p1 @ wp2 + bp2), O=64 -> s_b[0:256]
    {
        const int o  = tid & 63;
        const int rp = (tid >> 6) * 2;
        float b = bp2[o];
        float a0 = b, a1 = b;
        #pragma unroll 4
        for (int k = 0; k < 128; ++k) {
            float w = wp2[(size_t)k * 64 + o];
            a0 = fmaf(s_a[rp * 128 + k],       w, a0);
            a1 = fmaf(s_a[(rp + 1) * 128 + k], w, a1);
        }
        __syncthreads();             // all reads of s_b (xd) done
        s_b[rp * 64 + o]       = fmaxf(a0, 0.0f);
        s_b[(rp + 1) * 64 + o] = fmaxf(a1, 0.0f);
    }
    __syncthreads();

    // out = p2 @ wo + bo, O=5 (threads 0..19: r=tid/5, a=tid%5)
    if (tid < 20) {
        const int r = tid / 5, a = tid - r * 5;
        float acc = bo[a];
        #pragma unroll 8
        for (int k = 0; k < 64; ++k)
            acc = fmaf(s_b[r * 64 + k], wo[k * 5 + a], acc);
        out[(size_t)(row0 + r) * 5 + a] = acc;
    }
}

extern "C" void kernel_launch(void* const* d_in, const int* in_sizes, int n_in,
                              void* d_out, int out_size, void* d_ws, size_t ws_size,
                              hipStream_t stream)
{
    const float* x   = (const float*)d_in[0];
    const float* adj = (const float*)d_in[1];
    const float* w1  = (const float*)d_in[2];
    const float* b1  = (const float*)d_in[3];
    const float* w2  = (const float*)d_in[4];
    const float* b2  = (const float*)d_in[5];
    const float* wg  = (const float*)d_in[6];
    const float* bg  = (const float*)d_in[7];
    const float* wd  = (const float*)d_in[8];
    const float* bd  = (const float*)d_in[9];
    const float* wp1 = (const float*)d_in[10];
    const float* bp1 = (const float*)d_in[11];
    const float* wp2 = (const float*)d_in[12];
    const float* bp2 = (const float*)d_in[13];
    const float* wo  = (const float*)d_in[14];
    const float* bo  = (const float*)d_in[15];
    float* out = (float*)d_out;

    char* base = (char*)d_ws;
    // ws layout (~32.1 MB):
    float* h    = (float*)(base);                                  //  8 MB [N,128]
    float* hw   = (float*)(base + (8ull  << 20));                  //  8 MB [N,128]
    float* xg   = (float*)(base + (16ull << 20));                  //  8 MB [N,128]
    int*   cnts = (int*)  (base + (24ull << 20));                  // 64 KB
    int*   edges= (int*)  (base + (24ull << 20) + (64ull << 10));  //  8 MB [N,128]

    const int NB4 = N_NODES / 4;

    // Edge counters must start at 0 (ws arrives poisoned 0xAA).
    zero_cnts_kernel<<<N_NODES / 256, 256, 0, stream>>>(cnts);

    // Fused encoder: h = relu(relu(x@w1+b1)@w2+b2); hw = h@wg
    encoder_kernel<<<NB4, 128, 0, stream>>>(x, w1, b1, w2, b2, wg, h, hw);

    // Upper-triangle adjacency scan (537 MB HBM read, non-temporal) + GCN agg
    tri_scan_kernel<<<N_NODES, 256, 0, stream>>>(adj, edges, cnts);
    spmm_kernel<<<NB4, 128, 0, stream>>>(hw, edges, cnts, bg, xg);

    // Fused tail: xd -> p1 -> p2 -> out
    tail_kernel<<<NB4, 128, 0, stream>>>(xg, h, wd, bd, wp1, bp1, wp2, bp2,
                                         wo, bo, out);
}

// Round 2
// 1431.485 us; speedup vs baseline: 1.0069x; 1.0069x over previous
//
#include <hip/hip_runtime.h>
#include <hip/hip_bf16.h>

#define N_NODES 16384
#define EDGE_CAP 128   // max expected degree ~97 (mean 65.5, sd 8.1; >7 sigma headroom)

typedef float f32x4 __attribute__((ext_vector_type(4)));
typedef float f32x2 __attribute__((ext_vector_type(2)));

// ---------------------------------------------------------------------------
// Fused encoder: per 4-row block (128 threads), entirely in LDS:
//   h1 = relu(x@w1+b1)   [4,64]
//   h  = relu(h1@w2+b2)  [4,128]  -> global (tail needs it)
//   hw = h@wg            [4,128]  -> global (spmm needs it)
// Blocks 0..63 also zero the edge counters (ws arrives poisoned 0xAA),
// replacing the separate zero_cnts launch.
// ---------------------------------------------------------------------------
__global__ void encoder_kernel(const float* __restrict__ x,
                               const float* __restrict__ w1, const float* __restrict__ b1,
                               const float* __restrict__ w2, const float* __restrict__ b2,
                               const float* __restrict__ wg,
                               float* __restrict__ h, float* __restrict__ hw,
                               int* __restrict__ cnts)
{
    __shared__ float s_x [4 * 32];
    __shared__ float s_h1[4 * 64];
    __shared__ float s_h [4 * 128];
    const int row0 = blockIdx.x * 4;
    const int tid = threadIdx.x;     // 0..127

    if (blockIdx.x < 64) {           // 64 blocks x 256 = 16384 counters
        cnts[blockIdx.x * 256 + tid]       = 0;
        cnts[blockIdx.x * 256 + 128 + tid] = 0;
    }

    // stage x: 4 rows x 32 = 128 contiguous floats
    s_x[tid] = x[(size_t)row0 * 32 + tid];
    __syncthreads();

    // h1 = relu(x @ w1 + b1): O=64. threads 0..63 -> rows 0,1; 64..127 -> rows 2,3
    {
        const int o  = tid & 63;
        const int rp = (tid >> 6) * 2;
        float b = b1[o];
        float a0 = b, a1 = b;
        #pragma unroll
        for (int k = 0; k < 32; ++k) {
            float w = w1[k * 64 + o];
            a0 = fmaf(s_x[rp * 32 + k],       w, a0);
            a1 = fmaf(s_x[(rp + 1) * 32 + k], w, a1);
        }
        s_h1[rp * 64 + o]       = fmaxf(a0, 0.0f);
        s_h1[(rp + 1) * 64 + o] = fmaxf(a1, 0.0f);
    }
    __syncthreads();

    // h = relu(h1 @ w2 + b2): O=128, all 128 threads, 4 rows
    {
        const int o = tid;
        float b = b2[o];
        float a0 = b, a1 = b, a2 = b, a3 = b;
        #pragma unroll 4
        for (int k = 0; k < 64; ++k) {
            float w = w2[k * 128 + o];
            a0 = fmaf(s_h1[k],        w, a0);
            a1 = fmaf(s_h1[64 + k],   w, a1);
            a2 = fmaf(s_h1[128 + k],  w, a2);
            a3 = fmaf(s_h1[192 + k],  w, a3);
        }
        a0 = fmaxf(a0, 0.0f); a1 = fmaxf(a1, 0.0f);
        a2 = fmaxf(a2, 0.0f); a3 = fmaxf(a3, 0.0f);
        s_h[o] = a0;  s_h[128 + o] = a1;  s_h[256 + o] = a2;  s_h[384 + o] = a3;
        h[(size_t)(row0 + 0) * 128 + o] = a0;
        h[(size_t)(row0 + 1) * 128 + o] = a1;
        h[(size_t)(row0 + 2) * 128 + o] = a2;
        h[(size_t)(row0 + 3) * 128 + o] = a3;
    }
    __syncthreads();

    // hw = h @ wg (no bias, no relu)
    {
        const int o = tid;
        float a0 = 0.0f, a1 = 0.0f, a2 = 0.0f, a3 = 0.0f;
        #pragma unroll 4
        for (int k = 0; k < 128; ++k) {
            float w = wg[k * 128 + o];
            a0 = fmaf(s_h[k],        w, a0);
            a1 = fmaf(s_h[128 + k],  w, a1);
            a2 = fmaf(s_h[256 + k],  w, a2);
            a3 = fmaf(s_h[384 + k],  w, a3);
        }
        hw[(size_t)(row0 + 0) * 128 + o] = a0;
        hw[(size_t)(row0 + 1) * 128 + o] = a1;
        hw[(size_t)(row0 + 2) * 128 + o] = a2;
        hw[(size_t)(row0 + 3) * 128 + o] = a3;
    }
}

// ---------------------------------------------------------------------------
// Upper-triangle adjacency scan (adj symmetric, zero diagonal): block i scans
// columns j > i only (537 MB HBM read — the irreducible term). Row-i-side
// edges are aggregated in LDS and flushed with ONE base-reservation atomic +
// coalesced writes; only the j-side needs a per-edge global atomic + 4 B
// scattered write. Non-temporal loads keep the read-once adj stream from
// evicting hw (needed by the spmm phase next) out of L2/LLC.
// ---------------------------------------------------------------------------
__global__ void tri_scan_kernel(const float* __restrict__ adj,
                                int* __restrict__ edges,
                                int* __restrict__ cnts)
{
    __shared__ int s_cnt;
    __shared__ int s_base;
    __shared__ int s_list[EDGE_CAP];
    const int i = blockIdx.x;
    if (threadIdx.x == 0) s_cnt = 0;
    __syncthreads();

    const f32x4* rp = reinterpret_cast<const f32x4*>(adj + (size_t)i * N_NODES);
    const int v0 = (i + 1) >> 2;     // first float4 that can contain j > i
    for (int vi = v0 + threadIdx.x; vi < N_NODES / 4; vi += 256) {
        f32x4 v = __builtin_nontemporal_load(&rp[vi]);
        // 98.4% of float4s are all-zero: one branch skips the element loop
        if (v.x != 0.0f || v.y != 0.0f || v.z != 0.0f || v.w != 0.0f) {
            int base = vi * 4;
            #pragma unroll
            for (int q = 0; q < 4; ++q) {
                float val = (q == 0) ? v.x : (q == 1) ? v.y : (q == 2) ? v.z : v.w;
                int j = base + q;
                if (val != 0.0f && j > i) {
                    int p = atomicAdd(&s_cnt, 1);            // row-i side: LDS
                    if (p < EDGE_CAP) s_list[p] = j;
                    int pj = atomicAdd(&cnts[j], 1);         // row-j side: global
                    if (pj < EDGE_CAP) edges[(size_t)j * EDGE_CAP + pj] = i;
                }
            }
        }
    }
    __syncthreads();
    int c = s_cnt;
    if (c > EDGE_CAP) c = EDGE_CAP;                          // statistically impossible
    if (threadIdx.x == 0) s_base = atomicAdd(&cnts[i], c);
    __syncthreads();
    const int b = s_base;
    for (int k = threadIdx.x; k < c; k += 256) {
        int pos = b + k;
        if (pos < EDGE_CAP) edges[(size_t)i * EDGE_CAP + pos] = s_list[k];
    }
}

// ---------------------------------------------------------------------------
// Fused SpMM + tail MLP: 4 rows per block, 256 threads.
// Phase 1 (spmm): one WAVE per row (uniform trip count, no divergence);
//   each lane owns 2 features (float2 gathers of hw rows, L2/LLC resident).
//   xg = relu(dinv_i*(sum dinv_j*hw[j,:]) + bg) written straight to LDS —
//   the 16 MB xg global round-trip is gone.
// Phase 2 (tail): xd = relu(xg@wd+bd); p1 = relu([xd,h]@wp1+bp1);
//   p2 = relu(p1@wp2+bp2); out = p2@wo+bo. 256 threads -> 2 rows/thread
//   (halves per-thread VALU time vs the old 128-thread tail).
// ---------------------------------------------------------------------------
__global__ void spmm_tail_kernel(const float* __restrict__ hw,
                                 const int* __restrict__ edges,
                                 const int* __restrict__ cnts,
                                 const float* __restrict__ bg,
                                 const float* __restrict__ h,
                                 const float* __restrict__ wd,  const float* __restrict__ bd,
                                 const float* __restrict__ wp1, const float* __restrict__ bp1,
                                 const float* __restrict__ wp2, const float* __restrict__ bp2,
                                 const float* __restrict__ wo,  const float* __restrict__ bo,
                                 float* __restrict__ out)
{
    __shared__ int   s_e[4][EDGE_CAP];
    __shared__ float s_d[4][EDGE_CAP];
    __shared__ float s_a[4 * 128];   // xg, then p1
    __shared__ float s_h[4 * 128];   // h
    __shared__ float s_b[4 * 128];   // xd, then p2 (first 4*64)
    const int tid  = threadIdx.x;    // 0..255
    const int r    = tid >> 6;       // wave index == row within block
    const int lane = tid & 63;
    const int row0 = blockIdx.x * 4;
    const int row  = row0 + r;

    // stage h (independent of spmm): 512 floats / 256 threads
    s_h[tid]       = h[(size_t)row0 * 128 + tid];
    s_h[256 + tid] = h[(size_t)row0 * 128 + 256 + tid];

    // stage this wave's edge list + neighbor norms
    int c = cnts[row];
    if (c > EDGE_CAP) c = EDGE_CAP;
    for (int k = lane; k < c; k += 64) {
        int j = edges[(size_t)row * EDGE_CAP + k];
        s_e[r][k] = j;
        s_d[r][k] = rsqrtf((float)cnts[j] + 1.0f);
    }
    __syncthreads();

    // spmm: lane owns features {2*lane, 2*lane+1}
    const f32x2* hw2 = reinterpret_cast<const f32x2*>(hw);
    const float di = rsqrtf((float)c + 1.0f);
    f32x2 v = hw2[(size_t)row * 64 + lane];     // self loop
    f32x2 acc;
    acc.x = di * v.x;  acc.y = di * v.y;
    for (int k = 0; k < c; ++k) {
        float d = s_d[r][k];
        f32x2 u = hw2[(size_t)s_e[r][k] * 64 + lane];
        acc.x = fmaf(d, u.x, acc.x);
        acc.y = fmaf(d, u.y, acc.y);
    }
    {
        f32x2 bb = reinterpret_cast<const f32x2*>(bg)[lane];
        s_a[r * 128 + 2 * lane]     = fmaxf(fmaf(di, acc.x, bb.x), 0.0f);
        s_a[r * 128 + 2 * lane + 1] = fmaxf(fmaf(di, acc.y, bb.y), 0.0f);
    }
    __syncthreads();

    // xd = relu(xg @ wd + bd) -> s_b ; o=tid&127, rp: rows {0,1} or {2,3}
    {
        const int o  = tid & 127;
        const int rp = (tid >> 7) * 2;
        float b = bd[o];
        float a0 = b, a1 = b;
        #pragma unroll 4
        for (int k = 0; k < 128; ++k) {
            float w = wd[(size_t)k * 128 + o];
            a0 = fmaf(s_a[rp * 128 + k],       w, a0);
            a1 = fmaf(s_a[(rp + 1) * 128 + k], w, a1);
        }
        __syncthreads();             // all reads of s_a (xg) done
        s_b[rp * 128 + o]       = fmaxf(a0, 0.0f);
        s_b[(rp + 1) * 128 + o] = fmaxf(a1, 0.0f);
    }
    __syncthreads();

    // p1 = relu([xd, h] @ wp1 + bp1) -> s_a
    {
        const int o  = tid & 127;
        const int rp = (tid >> 7) * 2;
        float b = bp1[o];
        float a0 = b, a1 = b;
        #pragma unroll 4
        for (int k = 0; k < 128; ++k) {
            float w = wp1[(size_t)k * 128 + o];          // xd half
            a0 = fmaf(s_b[rp * 128 + k],       w, a0);
            a1 = fmaf(s_b[(rp + 1) * 128 + k], w, a1);
        }
        #pragma unroll 4
        for (int k = 0; k < 128; ++k) {
            float w = wp1[(size_t)(128 + k) * 128 + o];  // h half
            a0 = fmaf(s_h[rp * 128 + k],       w, a0);
            a1 = fmaf(s_h[(rp + 1) * 128 + k], w, a1);
        }
        s_a[rp * 128 + o]       = fmaxf(a0, 0.0f);
        s_a[(rp + 1) * 128 + o] = fmaxf(a1, 0.0f);
    }
    __syncthreads();

    // p2 = relu(p1 @ wp2 + bp2), O=64, 4 rows = 256 outputs, 1 per thread.
    // (p1-phase s_b reads all completed before the preceding barrier.)
    {
        const int o  = tid & 63;
        const int rr = tid >> 6;
        float a0 = bp2[o];
        #pragma unroll 4
        for (int k = 0; k < 128; ++k)
            a0 = fmaf(s_a[rr * 128 + k], wp2[(size_t)k * 64 + o], a0);
        s_b[rr * 64 + o] = fmaxf(a0, 0.0f);
    }
    __syncthreads();

    // out = p2 @ wo + bo, O=5 (threads 0..19: rr=tid/5, a=tid%5)
    if (tid < 20) {
        const int rr = tid / 5, a = tid - rr * 5;
        float acc2 = bo[a];
        #pragma unroll 8
        for (int k = 0; k < 64; ++k)
            acc2 = fmaf(s_b[rr * 64 + k], wo[k * 5 + a], acc2);
        out[(size_t)(row0 + rr) * 5 + a] = acc2;
    }
}

extern "C" void kernel_launch(void* const* d_in, const int* in_sizes, int n_in,
                              void* d_out, int out_size, void* d_ws, size_t ws_size,
                              hipStream_t stream)
{
    const float* x   = (const float*)d_in[0];
    const float* adj = (const float*)d_in[1];
    const float* w1  = (const float*)d_in[2];
    const float* b1  = (const float*)d_in[3];
    const float* w2  = (const float*)d_in[4];
    const float* b2  = (const float*)d_in[5];
    const float* wg  = (const float*)d_in[6];
    const float* bg  = (const float*)d_in[7];
    const float* wd  = (const float*)d_in[8];
    const float* bd  = (const float*)d_in[9];
    const float* wp1 = (const float*)d_in[10];
    const float* bp1 = (const float*)d_in[11];
    const float* wp2 = (const float*)d_in[12];
    const float* bp2 = (const float*)d_in[13];
    const float* wo  = (const float*)d_in[14];
    const float* bo  = (const float*)d_in[15];
    float* out = (float*)d_out;

    char* base = (char*)d_ws;
    // ws layout (~24.1 MB): xg buffer eliminated (lives in LDS now)
    float* h    = (float*)(base);                                  //  8 MB [N,128]
    float* hw   = (float*)(base + (8ull  << 20));                  //  8 MB [N,128]
    int*   cnts = (int*)  (base + (16ull << 20));                  // 64 KB
    int*   edges= (int*)  (base + (16ull << 20) + (64ull << 10));  //  8 MB [N,128]

    const int NB4 = N_NODES / 4;

    // Fused encoder (+ cnts zeroing): h = relu(relu(x@w1+b1)@w2+b2); hw = h@wg
    encoder_kernel<<<NB4, 128, 0, stream>>>(x, w1, b1, w2, b2, wg, h, hw, cnts);

    // Upper-triangle adjacency scan (537 MB HBM read, non-temporal)
    tri_scan_kernel<<<N_NODES, 256, 0, stream>>>(adj, edges, cnts);

    // Fused GCN aggregation + tail MLP -> out
    spmm_tail_kernel<<<NB4, 256, 0, stream>>>(hw, edges, cnts, bg, h,
                                              wd, bd, wp1, bp1, wp2, bp2,
                                              wo, bo, out);
}

// Round 3
// 1407.195 us; speedup vs baseline: 1.0243x; 1.0173x over previous
//
#include <hip/hip_runtime.h>
#include <hip/hip_bf16.h>

#define N_NODES 16384
#define EDGE_CAP 128   // max expected degree ~97 (mean 65.5, sd 8.1; >7 sigma headroom)

typedef float f32x4 __attribute__((ext_vector_type(4)));
typedef float f32x2 __attribute__((ext_vector_type(2)));

// ---------------------------------------------------------------------------
// Fused encoder: per 4-row block (128 threads), entirely in LDS:
//   h1 = relu(x@w1+b1)   [4,64]
//   h  = relu(h1@w2+b2)  [4,128]  -> global (tail needs it)
//   hw = h@wg            [4,128]  -> global (spmm needs it)
// Blocks 0..63 also zero the edge counters (ws arrives poisoned 0xAA).
// ---------------------------------------------------------------------------
__global__ void encoder_kernel(const float* __restrict__ x,
                               const float* __restrict__ w1, const float* __restrict__ b1,
                               const float* __restrict__ w2, const float* __restrict__ b2,
                               const float* __restrict__ wg,
                               float* __restrict__ h, float* __restrict__ hw,
                               int* __restrict__ cnts)
{
    __shared__ float s_x [4 * 32];
    __shared__ float s_h1[4 * 64];
    __shared__ float s_h [4 * 128];
    const int row0 = blockIdx.x * 4;
    const int tid = threadIdx.x;     // 0..127

    if (blockIdx.x < 64) {           // 64 blocks x 256 = 16384 counters
        cnts[blockIdx.x * 256 + tid]       = 0;
        cnts[blockIdx.x * 256 + 128 + tid] = 0;
    }

    // stage x: 4 rows x 32 = 128 contiguous floats
    s_x[tid] = x[(size_t)row0 * 32 + tid];
    __syncthreads();

    // h1 = relu(x @ w1 + b1): O=64. threads 0..63 -> rows 0,1; 64..127 -> rows 2,3
    {
        const int o  = tid & 63;
        const int rp = (tid >> 6) * 2;
        float b = b1[o];
        float a0 = b, a1 = b;
        #pragma unroll
        for (int k = 0; k < 32; ++k) {
            float w = w1[k * 64 + o];
            a0 = fmaf(s_x[rp * 32 + k],       w, a0);
            a1 = fmaf(s_x[(rp + 1) * 32 + k], w, a1);
        }
        s_h1[rp * 64 + o]       = fmaxf(a0, 0.0f);
        s_h1[(rp + 1) * 64 + o] = fmaxf(a1, 0.0f);
    }
    __syncthreads();

    // h = relu(h1 @ w2 + b2): O=128, all 128 threads, 4 rows
    {
        const int o = tid;
        float b = b2[o];
        float a0 = b, a1 = b, a2 = b, a3 = b;
        #pragma unroll 4
        for (int k = 0; k < 64; ++k) {
            float w = w2[k * 128 + o];
            a0 = fmaf(s_h1[k],        w, a0);
            a1 = fmaf(s_h1[64 + k],   w, a1);
            a2 = fmaf(s_h1[128 + k],  w, a2);
            a3 = fmaf(s_h1[192 + k],  w, a3);
        }
        a0 = fmaxf(a0, 0.0f); a1 = fmaxf(a1, 0.0f);
        a2 = fmaxf(a2, 0.0f); a3 = fmaxf(a3, 0.0f);
        s_h[o] = a0;  s_h[128 + o] = a1;  s_h[256 + o] = a2;  s_h[384 + o] = a3;
        h[(size_t)(row0 + 0) * 128 + o] = a0;
        h[(size_t)(row0 + 1) * 128 + o] = a1;
        h[(size_t)(row0 + 2) * 128 + o] = a2;
        h[(size_t)(row0 + 3) * 128 + o] = a3;
    }
    __syncthreads();

    // hw = h @ wg (no bias, no relu)
    {
        const int o = tid;
        float a0 = 0.0f, a1 = 0.0f, a2 = 0.0f, a3 = 0.0f;
        #pragma unroll 4
        for (int k = 0; k < 128; ++k) {
            float w = wg[k * 128 + o];
            a0 = fmaf(s_h[k],        w, a0);
            a1 = fmaf(s_h[128 + k],  w, a1);
            a2 = fmaf(s_h[256 + k],  w, a2);
            a3 = fmaf(s_h[384 + k],  w, a3);
        }
        hw[(size_t)(row0 + 0) * 128 + o] = a0;
        hw[(size_t)(row0 + 1) * 128 + o] = a1;
        hw[(size_t)(row0 + 2) * 128 + o] = a2;
        hw[(size_t)(row0 + 3) * 128 + o] = a3;
    }
}

// ---------------------------------------------------------------------------
// Upper-triangle adjacency scan, TWO-PHASE. The old version executed a
// dependent chain {global atomicAdd -> wait return -> scattered store} INSIDE
// the scan loop; since ~65% of wave-trips contain >=1 nonzero lane, nearly
// every trip paid a ~500-900 cyc unhideable stall. Phase 1 now touches only
// LDS (low-latency collect); phase 2 issues all j-side global atomics +
// scatters 128-wide in parallel so their latencies overlap across lanes.
// ---------------------------------------------------------------------------
__global__ void tri_scan_kernel(const float* __restrict__ adj,
                                int* __restrict__ edges,
                                int* __restrict__ cnts)
{
    __shared__ int s_cnt;
    __shared__ int s_base;
    __shared__ int s_list[EDGE_CAP];
    const int i = blockIdx.x;
    const int tid = threadIdx.x;
    if (tid == 0) s_cnt = 0;
    __syncthreads();

    // ---- phase 1: scan, LDS-only collection ----
    const f32x4* rp = reinterpret_cast<const f32x4*>(adj + (size_t)i * N_NODES);
    const int v0 = (i + 1) >> 2;     // first float4 that can contain j > i
    for (int vi = v0 + tid; vi < N_NODES / 4; vi += 256) {
        f32x4 v = __builtin_nontemporal_load(&rp[vi]);
        if (v.x != 0.0f || v.y != 0.0f || v.z != 0.0f || v.w != 0.0f) {
            int base = vi * 4;
            #pragma unroll
            for (int q = 0; q < 4; ++q) {
                float val = (q == 0) ? v.x : (q == 1) ? v.y : (q == 2) ? v.z : v.w;
                int j = base + q;
                if (val != 0.0f && j > i) {
                    int p = atomicAdd(&s_cnt, 1);
                    if (p < EDGE_CAP) s_list[p] = j;
                }
            }
        }
    }
    __syncthreads();

    // ---- phase 2: bulk global inserts ----
    int c = s_cnt;
    if (c > EDGE_CAP) c = EDGE_CAP;                   // statistically impossible
    if (tid == 0) s_base = atomicAdd(&cnts[i], c);    // i-side: ONE reservation

    // j-side: c <= 128 parallel atomic+scatter, latencies overlap
    for (int k = tid; k < c; k += 256) {
        int j = s_list[k];
        int pj = atomicAdd(&cnts[j], 1);
        if (pj < EDGE_CAP) edges[(size_t)j * EDGE_CAP + pj] = i;
    }
    __syncthreads();                                  // s_base visible

    const int b = s_base;
    for (int k = tid; k < c; k += 256) {
        int pos = b + k;
        if (pos < EDGE_CAP) edges[(size_t)i * EDGE_CAP + pos] = s_list[k];
    }
}

// ---------------------------------------------------------------------------
// Fused SpMM + tail MLP: 4 rows per block, 256 threads.
// Phase 1 (spmm): one WAVE per row; lane owns 2 features. Gather loop is
//   manually 4x-unrolled (4 independent dwordx2 gathers in flight before
//   their FMAs) with split accumulators -> latency-pipelined, not serial.
// Phase 2 (tail): xd -> p1 -> p2 -> out, entirely in LDS.
// ---------------------------------------------------------------------------
__global__ void spmm_tail_kernel(const float* __restrict__ hw,
                                 const int* __restrict__ edges,
                                 const int* __restrict__ cnts,
                                 const float* __restrict__ bg,
                                 const float* __restrict__ h,
                                 const float* __restrict__ wd,  const float* __restrict__ bd,
                                 const float* __restrict__ wp1, const float* __restrict__ bp1,
                                 const float* __restrict__ wp2, const float* __restrict__ bp2,
                                 const float* __restrict__ wo,  const float* __restrict__ bo,
                                 float* __restrict__ out)
{
    __shared__ int   s_e[4][EDGE_CAP];
    __shared__ float s_d[4][EDGE_CAP];
    __shared__ float s_a[4 * 128];   // xg, then p1
    __shared__ float s_h[4 * 128];   // h
    __shared__ float s_b[4 * 128];   // xd, then p2 (first 4*64)
    const int tid  = threadIdx.x;    // 0..255
    const int r    = tid >> 6;       // wave index == row within block
    const int lane = tid & 63;
    const int row0 = blockIdx.x * 4;
    const int row  = row0 + r;

    // stage h (independent of spmm): 512 floats / 256 threads
    s_h[tid]       = h[(size_t)row0 * 128 + tid];
    s_h[256 + tid] = h[(size_t)row0 * 128 + 256 + tid];

    // stage this wave's edge list + neighbor norms
    int c = cnts[row];
    if (c > EDGE_CAP) c = EDGE_CAP;
    for (int k = lane; k < c; k += 64) {
        int j = edges[(size_t)row * EDGE_CAP + k];
        s_e[r][k] = j;
        s_d[r][k] = rsqrtf((float)cnts[j] + 1.0f);
    }
    __syncthreads();

    // spmm: lane owns features {2*lane, 2*lane+1}; 4x unrolled gather
    const f32x2* hw2 = reinterpret_cast<const f32x2*>(hw);
    const float di = rsqrtf((float)c + 1.0f);
    f32x2 v = hw2[(size_t)row * 64 + lane];     // self loop
    float ax0 = di * v.x, ay0 = di * v.y;
    float ax1 = 0.0f,     ay1 = 0.0f;
    int k = 0;
    for (; k + 4 <= c; k += 4) {
        int j0 = s_e[r][k], j1 = s_e[r][k + 1], j2 = s_e[r][k + 2], j3 = s_e[r][k + 3];
        f32x2 u0 = hw2[(size_t)j0 * 64 + lane];
        f32x2 u1 = hw2[(size_t)j1 * 64 + lane];
        f32x2 u2 = hw2[(size_t)j2 * 64 + lane];
        f32x2 u3 = hw2[(size_t)j3 * 64 + lane];
        float d0 = s_d[r][k], d1 = s_d[r][k + 1], d2 = s_d[r][k + 2], d3 = s_d[r][k + 3];
        ax0 = fmaf(d0, u0.x, ax0);  ay0 = fmaf(d0, u0.y, ay0);
        ax1 = fmaf(d1, u1.x, ax1);  ay1 = fmaf(d1, u1.y, ay1);
        ax0 = fmaf(d2, u2.x, ax0);  ay0 = fmaf(d2, u2.y, ay0);
        ax1 = fmaf(d3, u3.x, ax1);  ay1 = fmaf(d3, u3.y, ay1);
    }
    for (; k < c; ++k) {
        float d = s_d[r][k];
        f32x2 u = hw2[(size_t)s_e[r][k] * 64 + lane];
        ax0 = fmaf(d, u.x, ax0);  ay0 = fmaf(d, u.y, ay0);
    }
    {
        f32x2 bb = reinterpret_cast<const f32x2*>(bg)[lane];
        s_a[r * 128 + 2 * lane]     = fmaxf(fmaf(di, ax0 + ax1, bb.x), 0.0f);
        s_a[r * 128 + 2 * lane + 1] = fmaxf(fmaf(di, ay0 + ay1, bb.y), 0.0f);
    }
    __syncthreads();

    // xd = relu(xg @ wd + bd) -> s_b ; o=tid&127, rp: rows {0,1} or {2,3}
    {
        const int o  = tid & 127;
        const int rp = (tid >> 7) * 2;
        float b = bd[o];
        float a0 = b, a1 = b;
        #pragma unroll 4
        for (int kk = 0; kk < 128; ++kk) {
            float w = wd[(size_t)kk * 128 + o];
            a0 = fmaf(s_a[rp * 128 + kk],       w, a0);
            a1 = fmaf(s_a[(rp + 1) * 128 + kk], w, a1);
        }
        __syncthreads();             // all reads of s_a (xg) done
        s_b[rp * 128 + o]       = fmaxf(a0, 0.0f);
        s_b[(rp + 1) * 128 + o] = fmaxf(a1, 0.0f);
    }
    __syncthreads();

    // p1 = relu([xd, h] @ wp1 + bp1) -> s_a
    {
        const int o  = tid & 127;
        const int rp = (tid >> 7) * 2;
        float b = bp1[o];
        float a0 = b, a1 = b;
        #pragma unroll 4
        for (int kk = 0; kk < 128; ++kk) {
            float w = wp1[(size_t)kk * 128 + o];          // xd half
            a0 = fmaf(s_b[rp * 128 + kk],       w, a0);
            a1 = fmaf(s_b[(rp + 1) * 128 + kk], w, a1);
        }
        #pragma unroll 4
        for (int kk = 0; kk < 128; ++kk) {
            float w = wp1[(size_t)(128 + kk) * 128 + o];  // h half
            a0 = fmaf(s_h[rp * 128 + kk],       w, a0);
            a1 = fmaf(s_h[(rp + 1) * 128 + kk], w, a1);
        }
        s_a[rp * 128 + o]       = fmaxf(a0, 0.0f);
        s_a[(rp + 1) * 128 + o] = fmaxf(a1, 0.0f);
    }
    __syncthreads();

    // p2 = relu(p1 @ wp2 + bp2), O=64, 4 rows = 256 outputs, 1 per thread
    {
        const int o  = tid & 63;
        const int rr = tid >> 6;
        float a0 = bp2[o];
        #pragma unroll 4
        for (int kk = 0; kk < 128; ++kk)
            a0 = fmaf(s_a[rr * 128 + kk], wp2[(size_t)kk * 64 + o], a0);
        s_b[rr * 64 + o] = fmaxf(a0, 0.0f);
    }
    __syncthreads();

    // out = p2 @ wo + bo, O=5 (threads 0..19: rr=tid/5, a=tid%5)
    if (tid < 20) {
        const int rr = tid / 5, a = tid - rr * 5;
        float acc2 = bo[a];
        #pragma unroll 8
        for (int kk = 0; kk < 64; ++kk)
            acc2 = fmaf(s_b[rr * 64 + kk], wo[kk * 5 + a], acc2);
        out[(size_t)(row0 + rr) * 5 + a] = acc2;
    }
}

extern "C" void kernel_launch(void* const* d_in, const int* in_sizes, int n_in,
                              void* d_out, int out_size, void* d_ws, size_t ws_size,
                              hipStream_t stream)
{
    const float* x   = (const float*)d_in[0];
    const float* adj = (const float*)d_in[1];
    const float* w1  = (const float*)d_in[2];
    const float* b1  = (const float*)d_in[3];
    const float* w2  = (const float*)d_in[4];
    const float* b2  = (const float*)d_in[5];
    const float* wg  = (const float*)d_in[6];
    const float* bg  = (const float*)d_in[7];
    const float* wd  = (const float*)d_in[8];
    const float* bd  = (const float*)d_in[9];
    const float* wp1 = (const float*)d_in[10];
    const float* bp1 = (const float*)d_in[11];
    const float* wp2 = (const float*)d_in[12];
    const float* bp2 = (const float*)d_in[13];
    const float* wo  = (const float*)d_in[14];
    const float* bo  = (const float*)d_in[15];
    float* out = (float*)d_out;

    char* base = (char*)d_ws;
    // ws layout (~24.1 MB)
    float* h    = (float*)(base);                                  //  8 MB [N,128]
    float* hw   = (float*)(base + (8ull  << 20));                  //  8 MB [N,128]
    int*   cnts = (int*)  (base + (16ull << 20));                  // 64 KB
    int*   edges= (int*)  (base + (16ull << 20) + (64ull << 10));  //  8 MB [N,128]

    const int NB4 = N_NODES / 4;

    // Fused encoder (+ cnts zeroing): h = relu(relu(x@w1+b1)@w2+b2); hw = h@wg
    encoder_kernel<<<NB4, 128, 0, stream>>>(x, w1, b1, w2, b2, wg, h, hw, cnts);

    // Two-phase upper-triangle adjacency scan (537 MB HBM read, non-temporal)
    tri_scan_kernel<<<N_NODES, 256, 0, stream>>>(adj, edges, cnts);

    // Fused GCN aggregation (pipelined gather) + tail MLP -> out
    spmm_tail_kernel<<<NB4, 256, 0, stream>>>(hw, edges, cnts, bg, h,
                                              wd, bd, wp1, bp1, wp2, bp2,
                                              wo, bo, out);
}